// Round 5
// baseline (118.949 us; speedup 1.0000x reference)
//
#include <hip/hip_runtime.h>
#include <math.h>

typedef unsigned short u16;
typedef unsigned int   u32;
typedef unsigned long long u64;
typedef __attribute__((ext_vector_type(4))) unsigned short u16x4;
typedef __attribute__((ext_vector_type(8))) unsigned short bf16x8;
typedef __attribute__((ext_vector_type(8))) short sh8;      // MFMA A/B frag (8 bf16)
typedef __attribute__((ext_vector_type(4))) float f32x4;    // MFMA C/D frag

#define BT     4096
#define D      2048
#define NC     8
#define NCOL   144     // 64 selW + 64 upd + 8 mu + 8 zero-pad (9 MFMA col-tiles)
#define NW     8       // waves per fused block = in-block K-split (R1 config: best)
#define KR     (D / NW)   // 256 per wave
#define TPB    16      // tokens per fused block
#define LPAD   (NCOL + 4) // LDS row pad (stride 148: kills pow2 bank pattern)

__device__ __forceinline__ float bf2f(u16 v) {
    u32 u = ((u32)v) << 16;
    float f; __builtin_memcpy(&f, &u, 4); return f;
}
__device__ __forceinline__ u16 f2bf(float f) {
    u32 u; __builtin_memcpy(&u, &f, 4);
    u += 0x7fffu + ((u >> 16) & 1);        // RNE
    return (u16)(u >> 16);
}

// ---------------------------------------------------------------------------
// Inline dtype detector (validated by A/B in prior session): fp32 bit
// patterns read as bf16 give |v|>1e4 or NaN w.p.~1; genuine bf16 N(0,1) stays
// |v|<6. All waves check the SAME 256 elements -> block-uniform flag.
// ---------------------------------------------------------------------------
__device__ __forceinline__ int detect_fp32(const void* xv) {
    const u16* p = (const u16*)xv;
    int l = threadIdx.x & 63;
    bool bad = false;
#pragma unroll
    for (int i = 0; i < 4; i++) {
        float v = bf2f(p[l * 4 + i]);
        if (!(fabsf(v) < 1e4f)) bad = true;   // catches NaN too
    }
    return __ballot(bad) != 0ull;
}

// ---- dtype-polymorphic loads: DT=0 bf16 buffers, DT=1 fp32 buffers ----
template<int DT> struct IO;
template<> struct IO<0> {
    static __device__ __forceinline__ float ld1(const void* p, size_t i) {
        return bf2f(((const u16*)p)[i]);
    }
    static __device__ __forceinline__ void ld4(const void* p, size_t i, float* o) {
        u16x4 v = *(const u16x4*)((const u16*)p + i);
#pragma unroll
        for (int k = 0; k < 4; k++) o[k] = bf2f(v[k]);
    }
    static __device__ __forceinline__ void ld8(const void* p, size_t i, float* o) {
        bf16x8 v = *(const bf16x8*)((const u16*)p + i);
#pragma unroll
        for (int k = 0; k < 8; k++) o[k] = bf2f(v[k]);
    }
    static __device__ __forceinline__ void st4(void* p, size_t i, const float* v) {
        u16x4 o;
#pragma unroll
        for (int k = 0; k < 4; k++) o[k] = f2bf(v[k]);
        *(u16x4*)((u16*)p + i) = o;
    }
    static __device__ __forceinline__ u16 ldbf(const void* p, size_t i) {
        return ((const u16*)p)[i];
    }
    static __device__ __forceinline__ sh8 afrag(const void* p, size_t i) {
        return *(const sh8*)((const u16*)p + i);
    }
};
template<> struct IO<1> {
    static __device__ __forceinline__ float ld1(const void* p, size_t i) {
        return ((const float*)p)[i];
    }
    static __device__ __forceinline__ void ld4(const void* p, size_t i, float* o) {
        f32x4 a = *(const f32x4*)((const float*)p + i);
#pragma unroll
        for (int k = 0; k < 4; k++) o[k] = a[k];
    }
    static __device__ __forceinline__ void ld8(const void* p, size_t i, float* o) {
        f32x4 a = *(const f32x4*)((const float*)p + i);
        f32x4 b = *(const f32x4*)((const float*)p + i + 4);
#pragma unroll
        for (int k = 0; k < 4; k++) { o[k] = a[k]; o[4 + k] = b[k]; }
    }
    static __device__ __forceinline__ void st4(void* p, size_t i, const float* v) {
        f32x4 a;
#pragma unroll
        for (int k = 0; k < 4; k++) a[k] = v[k];
        *(f32x4*)((float*)p + i) = a;
    }
    static __device__ __forceinline__ u16 ldbf(const void* p, size_t i) {
        return f2bf(((const float*)p)[i]);
    }
    static __device__ __forceinline__ sh8 afrag(const void* p, size_t i) {
        f32x4 a = *(const f32x4*)((const float*)p + i);
        f32x4 b = *(const f32x4*)((const float*)p + i + 4);
        sh8 r;
#pragma unroll
        for (int k = 0; k < 4; k++) {
            r[k]     = (short)f2bf(a[k]);
            r[4 + k] = (short)f2bf(b[k]);
        }
        return r;
    }
};

// ---------------------------------------------------------------------------
// k_prep (272 blocks):
//  0..143 : WtT bf16 in FRAG-MAJOR layout (R4): frag (w,ks,ct) = the 1 KB
//           contiguous block of the MFMA B-fragment read by k_fused's wave w
//           at k-step ks, col-tile ct. Lane l's 16 B live at
//           WtT[(((w*8+ks)*9+ct)*64 + l)*8]. Logical content is unchanged:
//           rows 0..63 selW[n][:,s], 64..127 upd[n][:,h], 128..135 mu[n],
//           136..143 zeros (row j, col d0 -> ct=j>>4, m=j&15, w=d0>>8,
//           ks=(d0>>5)&7, q=(d0>>3)&3, l=q*16+m). This turns the gemm's
//           9 scattered 16-line loads per k-step into one sequential 9 KB
//           stream per k-step (72 KB/wave) -> dense full-width L2 requests.
//  144..207: per-concept const PARTIALS — plain-stored gPart[pid][17]
//  208..271: DGN -> bf16 repack (halves blend's L2 traffic)
// ---------------------------------------------------------------------------
template<int DT>
__device__ __forceinline__ void prep_part(const void* selW, const void* upd,
                                          const void* mu, u16* __restrict__ WtT) {
    int idx = blockIdx.x * 256 + threadIdx.x;
    int j = idx >> 8, d0 = (idx & 255) * 8;
    bf16x8 v;
    if (j < 64) {
        int n = j >> 3, s = j & 7;
#pragma unroll
        for (int i = 0; i < 8; i++) v[i] = IO<DT>::ldbf(selW, ((size_t)n * D + d0 + i) * 8 + s);
    } else if (j < 128) {
        int n = (j - 64) >> 3, h = j & 7;
#pragma unroll
        for (int i = 0; i < 8; i++) v[i] = IO<DT>::ldbf(upd, ((size_t)n * D + d0 + i) * 8 + h);
    } else if (j < 136) {
#pragma unroll
        for (int i = 0; i < 8; i++) v[i] = IO<DT>::ldbf(mu, (size_t)(j - 128) * D + d0 + i);
    } else {
#pragma unroll
        for (int i = 0; i < 8; i++) v[i] = 0;
    }
    // frag-major destination (pure permutation of the old [144][2048] layout)
    int ct = j >> 4, m = j & 15;
    int w  = d0 >> 8, ks = (d0 >> 5) & 7, q = (d0 >> 3) & 3;
    size_t dst = ((((size_t)(w * 8 + ks) * 9 + ct) * 64) + q * 16 + m) * 8;
    *(bf16x8*)(WtT + dst) = v;
}

template<int DT>
__device__ __forceinline__ void consts_part(const void* W, const void* mu,
                                            const void* upd, const void* deb,
                                            float* __restrict__ gPart) {
    int pid = blockIdx.x - 144;            // 0..63 = (n<<3)|chunk
    int n = pid >> 3, t = threadIdx.x;
    int d = (pid & 7) * 256 + t;

    float mud = IO<DT>::ld1(mu,  (size_t)n * D + d);
    float dbd = IO<DT>::ld1(deb, (size_t)n * D + d);
    float m2 = mud * mud;
    float wv[8], uv[8], o[8], u[8];
    IO<DT>::ld8(W,   ((size_t)n * D + d) * 8, wv);
    IO<DT>::ld8(upd, ((size_t)n * D + d) * 8, uv);
#pragma unroll
    for (int s = 0; s < 8; s++) { o[s] = wv[s] * mud; u[s] = uv[s] * dbd; }

#pragma unroll
    for (int i = 1; i < 64; i <<= 1) {
        m2 += __shfl_xor(m2, i, 64);
#pragma unroll
        for (int s = 0; s < 8; s++) {
            o[s] += __shfl_xor(o[s], i, 64);
            u[s] += __shfl_xor(u[s], i, 64);
        }
    }
    __shared__ float red[4][17];
    int wave = t >> 6, lane = t & 63;
    if (lane == 0) {
        red[wave][0] = m2;
#pragma unroll
        for (int s = 0; s < 8; s++) { red[wave][1 + s] = o[s]; red[wave][9 + s] = u[s]; }
    }
    __syncthreads();
    if (t < 17) {
        float acc = red[0][t] + red[1][t] + red[2][t] + red[3][t];
        gPart[pid * 17 + t] = acc;         // plain store — block owns its slot
    }
}

template<int DT>
__device__ __forceinline__ void dgnb_part(const void* dgn, u16* __restrict__ dgnb) {
    int idx = (blockIdx.x - 208) * 256 + threadIdx.x;   // 16384 threads x 8 elems
    float v[8];
    IO<DT>::ld8(dgn, (size_t)idx * 8, v);
    bf16x8 o;
#pragma unroll
    for (int k = 0; k < 8; k++) o[k] = f2bf(v[k]);
    *(bf16x8*)(dgnb + (size_t)idx * 8) = o;
}

__global__ __launch_bounds__(256) void k_prep(
    const void* x, const void* selW, const void* upd, const void* mu,
    const void* deb, const void* dgn, u16* WtT, float* gPart, u16* dgnb) {
    int f = detect_fp32(x);
    if (blockIdx.x < 144) {
        if (f) prep_part<1>(selW, upd, mu, WtT); else prep_part<0>(selW, upd, mu, WtT);
    } else if (blockIdx.x < 208) {
        if (f) consts_part<1>(selW, mu, upd, deb, gPart);
        else   consts_part<0>(selW, mu, upd, deb, gPart);
    } else {
        if (f) dgnb_part<1>(dgn, dgnb); else dgnb_part<0>(dgn, dgnb);
    }
}

// ---------------------------------------------------------------------------
// k_fused (256 blocks x 512 threads): gemm + gate + blend, 16 tokens/block.
//  R5 change vs R4: __launch_bounds__(512, 2). R4's VGPR_Count=64 showed the
//  compiler was targeting 8 waves/SIMD (<=64 VGPR) although the grid only
//  provides 2 waves/SIMD — the gemm loop (36 acc + 36 B-frag + 4 A VGPRs per
//  k-step, x2 for the unroll-2 hoist) was register-starved into shallow load
//  batches. min-waves/EU=2 raises the cap to 128 VGPR so a full 2-k-step
//  load pipeline stays in flight against the frag-major B stream.
//  Phase 1 (gemm): wave w owns K-slice [w*256, +256); MFMA 16x16x32
//    (A: lane l holds X[tok0+(l&15)][k0+(l>>4)*8..+8]; C/D row=(l>>4)*4+reg,
//    col=l&15). Partial 16x144 tile -> per-wave LDS slab.
//  Phase 2 (gate): 128 threads (tok,n), verified score/argmax/tie-break.
//  Phase 3 (blend): 512 threads x 4 d's, 16-token loop, coalesced.
// ---------------------------------------------------------------------------
template<int DT>
__device__ __forceinline__ void fused_body(
    const void* X, const u16* __restrict__ WtT, const float* __restrict__ gPart,
    const u16* __restrict__ DGNB, const void* BIAS,
    const void* CENTER, const void* SLOPE, void* OUT,
    float (*LP)[TPB][LPAD], float (*LS2)[TPB],
    float (*cOFF)[8], float (*cUB)[8], float* cMU2,
    float (*mxL)[8], float* svalL, int* cL) {

    const int t = threadIdx.x;
    const int w = t >> 6, l = t & 63;
    const int m = l & 15, q = l >> 4;
    const int tok0 = blockIdx.x * TPB;
    const int k0 = w * KR;

    // consts: sum the 8 per-chunk partials per concept into LDS (t<136).
    // Ordered before gate reads by the post-gemm barrier.
    if (t < 136) {
        int n = t / 17, k = t % 17;
        float s = 0.f;
#pragma unroll
        for (int j = 0; j < 8; j++) s += gPart[(n * 8 + j) * 17 + k];
        if (k == 0)      cMU2[n] = s;
        else if (k < 9)  cOFF[n][k - 1] = s;
        else             cUB[n][k - 9] = s;
    }

    // ---- phase 1: gemm over this wave's K slice ----
    const size_t aoff = (size_t)(tok0 + m) * D + k0 + q * 8;
    // frag-major B: wave w's stream starts at frag (w*8, ct=0); lane offset l*8
    const u16* bp = WtT + (size_t)w * (8 * 9 * 512) + (size_t)l * 8;

    f32x4 acc[9];
#pragma unroll
    for (int ct = 0; ct < 9; ct++) acc[ct] = (f32x4){0.f, 0.f, 0.f, 0.f};
    float s2 = 0.f;

#pragma unroll 2
    for (int ks = 0; ks < KR / 32; ks++) {
        sh8 a = IO<DT>::afrag(X, aoff + ks * 32);
        sh8 b[9];
#pragma unroll
        for (int ct = 0; ct < 9; ct++)
            b[ct] = *(const sh8*)(bp + (size_t)(ks * 9 + ct) * 512);
#pragma unroll
        for (int i = 0; i < 8; i++) {
            float xv = bf2f((u16)a[i]);
            s2 = fmaf(xv, xv, s2);
        }
#pragma unroll
        for (int ct = 0; ct < 9; ct++)
            acc[ct] = __builtin_amdgcn_mfma_f32_16x16x32_bf16(a, b[ct], acc[ct], 0, 0, 0);
    }

    // per-token partial sum(x^2) over this K slice: reduce over q
    s2 += __shfl_xor(s2, 16, 64);
    s2 += __shfl_xor(s2, 32, 64);
    if (l < 16) LS2[w][l] = s2;

    // partial P tile -> this wave's LDS slab (2-way bank alias only: free)
#pragma unroll
    for (int ct = 0; ct < 9; ct++)
#pragma unroll
        for (int r = 0; r < 4; r++)
            LP[w][q * 4 + r][ct * 16 + m] = acc[ct][r];
    __syncthreads();

    // ---- phase 2: gate (128 threads = 16 tokens x 8 concepts) ----
    if (t < 128) {
        const int tok = t >> 3, n = t & 7;
        float sx2 = 0.f;
#pragma unroll
        for (int u = 0; u < NW; u++) sx2 += LS2[u][tok];

        float pa[8];
#pragma unroll
        for (int s = 0; s < 8; s++) {
            float v = 0.f;
#pragma unroll
            for (int u = 0; u < NW; u++) v += LP[u][tok][n * 8 + s];
            pa[s] = v;
        }
        float mdot = 0.f;
#pragma unroll
        for (int u = 0; u < NW; u++) mdot += LP[u][tok][128 + n];

        float norm2 = sx2 - 2.f * mdot + cMU2[n];
        float sc = 0.f;
#pragma unroll
        for (int s = 0; s < 8; s++) {
            float dd = pa[s] - cOFF[n][s];
            sc += dd * dd;
        }
        sc /= norm2;
        float zv = IO<DT>::ld1(SLOPE, n) * (sc - IO<DT>::ld1(CENTER, n));
        int iv = n;
#pragma unroll
        for (int i = 1; i < 8; i <<= 1) {          // first-max tie-break == np.argmax
            float z2 = __shfl_xor(zv, i, 64);
            int   i2 = __shfl_xor(iv, i, 64);
            if (z2 > zv || (z2 == zv && i2 < iv)) { zv = z2; iv = i2; }
        }
        const int c = iv;
        float mxv = 0.f;
#pragma unroll
        for (int u = 0; u < NW; u++) mxv += LP[u][tok][64 + c * 8 + n];
        mxL[tok][n] = mxv - cUB[c][n];
        if (n == 0) { svalL[tok] = 1.f / (1.f + expf(-zv)); cL[tok] = c; }
    }
    __syncthreads();

    // ---- phase 3: blend (512 threads x 4 d's, 16-token loop) ----
    const int d0 = t * 4;
    for (int tok = 0; tok < TPB; ++tok) {
        const int c = cL[tok];
        const float sval = svalL[tok];
        float mxa[8];
#pragma unroll
        for (int h = 0; h < 8; h++) mxa[h] = mxL[tok][h];   // LDS broadcast

        const size_t trow = (size_t)(tok0 + tok) * D;
        float xf[4], bv[4], ov[4];
        IO<DT>::ld4(X,    trow + d0, xf);
        IO<DT>::ld4(BIAS, (size_t)c * D + d0, bv);
#pragma unroll
        for (int i = 0; i < 4; i++) {
            bf16x8 v = *(const bf16x8*)(DGNB + ((size_t)c * D + d0 + i) * 8);
            float du = bf2f(v[0]) * mxa[0] + bf2f(v[1]) * mxa[1]
                     + bf2f(v[2]) * mxa[2] + bf2f(v[3]) * mxa[3]
                     + bf2f(v[4]) * mxa[4] + bf2f(v[5]) * mxa[5]
                     + bf2f(v[6]) * mxa[6] + bf2f(v[7]) * mxa[7];
            ov[i] = (1.f - sval) * xf[i] + sval * (bv[i] + du);   // ETA = 1.0
        }
        IO<DT>::st4(OUT, trow + d0, ov);
    }
}

__global__ __launch_bounds__(512, 2) void k_fused(
    const void* X, const u16* WtT, const float* gPart, const u16* DGNB,
    const void* BIAS, const void* CENTER, const void* SLOPE, void* OUT) {
    __shared__ float LP[NW][TPB][LPAD];      // 75.8 KB: 8 partial 16x144 tiles
    __shared__ float LS2[NW][TPB];
    __shared__ float cOFF[8][8], cUB[8][8], cMU2[8];
    __shared__ float mxL[TPB][8], svalL[TPB];
    __shared__ int   cL[TPB];
    if (detect_fp32(X))
        fused_body<1>(X, WtT, gPart, DGNB, BIAS, CENTER, SLOPE, OUT,
                      LP, LS2, cOFF, cUB, cMU2, mxL, svalL, cL);
    else
        fused_body<0>(X, WtT, gPart, DGNB, BIAS, CENTER, SLOPE, OUT,
                      LP, LS2, cOFF, cUB, cMU2, mxL, svalL, cL);
}

// ---------------------------------------------------------------------------
extern "C" void kernel_launch(void* const* d_in, const int* in_sizes, int n_in,
                              void* d_out, int out_size, void* d_ws, size_t ws_size,
                              hipStream_t stream) {
    const void* x      = d_in[0];
    const void* selW   = d_in[1];
    const void* mu     = d_in[2];
    const void* center = d_in[3];
    const void* slope  = d_in[4];
    const void* upd    = d_in[5];
    const void* dgn    = d_in[6];
    const void* biasW  = d_in[7];
    const void* debW   = d_in[8];

    // ws: WtT 576 KB + dgnb 256 KB + gPart 4.3 KB  (~840 KB total).
    // K-reduction + gate live entirely in LDS; no memset dispatch.
    char* ws = (char*)d_ws;
    u16*   WtT   = (u16*)ws;                      // 589824 B
    u16*   dgnb  = (u16*)(ws + 589824);           // 262144 B
    float* gPart = (float*)(ws + 851968);         //   4352 B

    k_prep <<<272, 256, 0, stream>>>(x, selW, upd, mu, debW, dgn, WtT, gPart, dgnb);
    k_fused<<<BT / TPB, 512, 0, stream>>>(x, WtT, gPart, dgnb, biasW, center, slope, d_out);
}

// Round 6
// 115.822 us; speedup vs baseline: 1.0270x; 1.0270x over previous
//
#include <hip/hip_runtime.h>
#include <math.h>

typedef unsigned short u16;
typedef unsigned int   u32;
typedef unsigned long long u64;
typedef __attribute__((ext_vector_type(4))) unsigned short u16x4;
typedef __attribute__((ext_vector_type(8))) unsigned short bf16x8;
typedef __attribute__((ext_vector_type(8))) short sh8;      // MFMA A/B frag (8 bf16)
typedef __attribute__((ext_vector_type(4))) float f32x4;    // MFMA C/D frag

#define BT     4096
#define D      2048
#define NC     8
#define NCOL   144     // 64 selW + 64 upd + 8 mu + 8 zero-pad (9 MFMA col-tiles)
#define NW     8       // waves per fused block = in-block K-split
#define KR     (D / NW)   // 256 per wave
#define TPB    16      // tokens per fused block
#define LPAD   (NCOL + 4) // LP row pad (stride 148: kills pow2 bank pattern)

// LDS geometry (u16 units): per-wave staging slab = 2 bufs x 9 frags x 512 u16
#define FRAGU  512                  // u16 per fragment (64 lanes x 16 B)
#define BUFU   (9 * FRAGU)          // 4608 u16 = 9 KB per k-step buffer
#define SLABU  (2 * BUFU)           // 9216 u16 = 18 KB per wave

__device__ __forceinline__ float bf2f(u16 v) {
    u32 u = ((u32)v) << 16;
    float f; __builtin_memcpy(&f, &u, 4); return f;
}
__device__ __forceinline__ u16 f2bf(float f) {
    u32 u; __builtin_memcpy(&u, &f, 4);
    u += 0x7fffu + ((u >> 16) & 1);        // RNE
    return (u16)(u >> 16);
}

// ---------------------------------------------------------------------------
// Inline dtype detector (validated by A/B in prior session): fp32 bit
// patterns read as bf16 give |v|>1e4 or NaN w.p.~1; genuine bf16 N(0,1) stays
// |v|<6. All waves check the SAME 256 elements -> block-uniform flag.
// ---------------------------------------------------------------------------
__device__ __forceinline__ int detect_fp32(const void* xv) {
    const u16* p = (const u16*)xv;
    int l = threadIdx.x & 63;
    bool bad = false;
#pragma unroll
    for (int i = 0; i < 4; i++) {
        float v = bf2f(p[l * 4 + i]);
        if (!(fabsf(v) < 1e4f)) bad = true;   // catches NaN too
    }
    return __ballot(bad) != 0ull;
}

// ---- dtype-polymorphic loads: DT=0 bf16 buffers, DT=1 fp32 buffers ----
template<int DT> struct IO;
template<> struct IO<0> {
    static __device__ __forceinline__ float ld1(const void* p, size_t i) {
        return bf2f(((const u16*)p)[i]);
    }
    static __device__ __forceinline__ void ld4(const void* p, size_t i, float* o) {
        u16x4 v = *(const u16x4*)((const u16*)p + i);
#pragma unroll
        for (int k = 0; k < 4; k++) o[k] = bf2f(v[k]);
    }
    static __device__ __forceinline__ void ld8(const void* p, size_t i, float* o) {
        bf16x8 v = *(const bf16x8*)((const u16*)p + i);
#pragma unroll
        for (int k = 0; k < 8; k++) o[k] = bf2f(v[k]);
    }
    static __device__ __forceinline__ void st4(void* p, size_t i, const float* v) {
        u16x4 o;
#pragma unroll
        for (int k = 0; k < 4; k++) o[k] = f2bf(v[k]);
        *(u16x4*)((u16*)p + i) = o;
    }
    static __device__ __forceinline__ u16 ldbf(const void* p, size_t i) {
        return ((const u16*)p)[i];
    }
};
template<> struct IO<1> {
    static __device__ __forceinline__ float ld1(const void* p, size_t i) {
        return ((const float*)p)[i];
    }
    static __device__ __forceinline__ void ld4(const void* p, size_t i, float* o) {
        f32x4 a = *(const f32x4*)((const float*)p + i);
#pragma unroll
        for (int k = 0; k < 4; k++) o[k] = a[k];
    }
    static __device__ __forceinline__ void ld8(const void* p, size_t i, float* o) {
        f32x4 a = *(const f32x4*)((const float*)p + i);
        f32x4 b = *(const f32x4*)((const float*)p + i + 4);
#pragma unroll
        for (int k = 0; k < 4; k++) { o[k] = a[k]; o[4 + k] = b[k]; }
    }
    static __device__ __forceinline__ void st4(void* p, size_t i, const float* v) {
        f32x4 a;
#pragma unroll
        for (int k = 0; k < 4; k++) a[k] = v[k];
        *(f32x4*)((float*)p + i) = a;
    }
    static __device__ __forceinline__ u16 ldbf(const void* p, size_t i) {
        return f2bf(((const float*)p)[i]);
    }
};

// ---------------------------------------------------------------------------
// k_prep (272 blocks) — unchanged from R4/R5 (frag-major WtT):
//  0..143 : WtT bf16 FRAG-MAJOR: frag (w,ks,ct) is a contiguous 1 KB block,
//           lane l's 16 B at WtT[(((w*8+ks)*9+ct)*64 + l)*8]. Content: rows
//           0..63 selW[n][:,s], 64..127 upd[n][:,h], 128..135 mu[n],
//           136..143 zeros. Exactly the base+lane*16 order global_load_lds
//           writes — so k_fused can DMA whole fragments to LDS.
//  144..207: per-concept const PARTIALS — plain-stored gPart[pid][17]
//  208..271: DGN -> bf16 repack (halves blend's L2 traffic)
// ---------------------------------------------------------------------------
template<int DT>
__device__ __forceinline__ void prep_part(const void* selW, const void* upd,
                                          const void* mu, u16* __restrict__ WtT) {
    int idx = blockIdx.x * 256 + threadIdx.x;
    int j = idx >> 8, d0 = (idx & 255) * 8;
    bf16x8 v;
    if (j < 64) {
        int n = j >> 3, s = j & 7;
#pragma unroll
        for (int i = 0; i < 8; i++) v[i] = IO<DT>::ldbf(selW, ((size_t)n * D + d0 + i) * 8 + s);
    } else if (j < 128) {
        int n = (j - 64) >> 3, h = j & 7;
#pragma unroll
        for (int i = 0; i < 8; i++) v[i] = IO<DT>::ldbf(upd, ((size_t)n * D + d0 + i) * 8 + h);
    } else if (j < 136) {
#pragma unroll
        for (int i = 0; i < 8; i++) v[i] = IO<DT>::ldbf(mu, (size_t)(j - 128) * D + d0 + i);
    } else {
#pragma unroll
        for (int i = 0; i < 8; i++) v[i] = 0;
    }
    // frag-major destination (pure permutation of the old [144][2048] layout)
    int ct = j >> 4, m = j & 15;
    int w  = d0 >> 8, ks = (d0 >> 5) & 7, q = (d0 >> 3) & 3;
    size_t dst = ((((size_t)(w * 8 + ks) * 9 + ct) * 64) + q * 16 + m) * 8;
    *(bf16x8*)(WtT + dst) = v;
}

template<int DT>
__device__ __forceinline__ void consts_part(const void* W, const void* mu,
                                            const void* upd, const void* deb,
                                            float* __restrict__ gPart) {
    int pid = blockIdx.x - 144;            // 0..63 = (n<<3)|chunk
    int n = pid >> 3, t = threadIdx.x;
    int d = (pid & 7) * 256 + t;

    float mud = IO<DT>::ld1(mu,  (size_t)n * D + d);
    float dbd = IO<DT>::ld1(deb, (size_t)n * D + d);
    float m2 = mud * mud;
    float wv[8], uv[8], o[8], u[8];
    IO<DT>::ld8(W,   ((size_t)n * D + d) * 8, wv);
    IO<DT>::ld8(upd, ((size_t)n * D + d) * 8, uv);
#pragma unroll
    for (int s = 0; s < 8; s++) { o[s] = wv[s] * mud; u[s] = uv[s] * dbd; }

#pragma unroll
    for (int i = 1; i < 64; i <<= 1) {
        m2 += __shfl_xor(m2, i, 64);
#pragma unroll
        for (int s = 0; s < 8; s++) {
            o[s] += __shfl_xor(o[s], i, 64);
            u[s] += __shfl_xor(u[s], i, 64);
        }
    }
    __shared__ float red[4][17];
    int wave = t >> 6, lane = t & 63;
    if (lane == 0) {
        red[wave][0] = m2;
#pragma unroll
        for (int s = 0; s < 8; s++) { red[wave][1 + s] = o[s]; red[wave][9 + s] = u[s]; }
    }
    __syncthreads();
    if (t < 17) {
        float acc = red[0][t] + red[1][t] + red[2][t] + red[3][t];
        gPart[pid * 17 + t] = acc;         // plain store — block owns its slot
    }
}

template<int DT>
__device__ __forceinline__ void dgnb_part(const void* dgn, u16* __restrict__ dgnb) {
    int idx = (blockIdx.x - 208) * 256 + threadIdx.x;   // 16384 threads x 8 elems
    float v[8];
    IO<DT>::ld8(dgn, (size_t)idx * 8, v);
    bf16x8 o;
#pragma unroll
    for (int k = 0; k < 8; k++) o[k] = f2bf(v[k]);
    *(bf16x8*)(dgnb + (size_t)idx * 8) = o;
}

__global__ __launch_bounds__(256) void k_prep(
    const void* x, const void* selW, const void* upd, const void* mu,
    const void* deb, const void* dgn, u16* WtT, float* gPart, u16* dgnb) {
    int f = detect_fp32(x);
    if (blockIdx.x < 144) {
        if (f) prep_part<1>(selW, upd, mu, WtT); else prep_part<0>(selW, upd, mu, WtT);
    } else if (blockIdx.x < 208) {
        if (f) consts_part<1>(selW, mu, upd, deb, gPart);
        else   consts_part<0>(selW, mu, upd, deb, gPart);
    } else {
        if (f) dgnb_part<1>(dgn, dgnb); else dgnb_part<0>(dgn, dgnb);
    }
}

// async global->LDS DMA, 16 B per lane (guide m97: width=16 verified gfx950)
#define GLL16(gp, lp)                                                          \
    __builtin_amdgcn_global_load_lds(                                          \
        (const __attribute__((address_space(1))) u32*)(gp),                    \
        (__attribute__((address_space(3))) u32*)(lp), 16, 0, 0)

// ---------------------------------------------------------------------------
// k_fused (256 blocks x 512 threads): gemm + gate + blend, 16 tokens/block.
//  R6 change vs R5: the gemm's B stream is staged via global_load_lds into a
//  per-wave double-buffered LDS slab with a COUNTED s_waitcnt vmcnt(N) —
//  k-step k+1's 9 fragment-DMAs (+2 raw A loads) stay in flight while k-step
//  k computes (cp.async-style; never vmcnt(0) mid-loop). This decouples
//  outstanding-load depth from VGPR liveness — R2/R5 proved neither waves
//  nor VGPR cap were the limiter; un-hidden load latency was.
//  Frag-major WtT (R4) is exactly the base+lane*16 DMA layout, so LDS stays
//  linear (guide m104 caveat satisfied). The per-wave LP slab (9.25 KB)
//  OVERLAYS its own 18 KB staging slab — safe: DS ops are in-order per wave
//  and LP writes follow the last staged-buffer reads.
//  A-frags prefetch RAW into named regs, convert after the wait (no early
//  drain). Numerics of all phases byte-identical to R5.
// ---------------------------------------------------------------------------
template<int DT>
__device__ __forceinline__ void fused_body(
    const void* X, const u16* __restrict__ WtT, const float* __restrict__ gPart,
    const u16* __restrict__ DGNB, const void* BIAS,
    const void* CENTER, const void* SLOPE, void* OUT,
    u16* BS, float (*LS2)[TPB],
    float (*cOFF)[8], float (*cUB)[8], float* cMU2,
    float (*mxL)[8], float* svalL, int* cL) {

    const int t = threadIdx.x;
    const int w = t >> 6, l = t & 63;
    const int m = l & 15, q = l >> 4;
    const int tok0 = blockIdx.x * TPB;
    const int k0 = w * KR;

    // ---- phase 1: gemm over this wave's K slice, async-staged B ----
    const size_t aoff = (size_t)(tok0 + m) * D + k0 + q * 8;
    const u16* gB = WtT + (size_t)w * (8 * 9 * FRAGU);   // wave's 72 KB B stream
    u16* sB = BS + w * SLABU;                            // wave's LDS slab

    f32x4 acc[9];
#pragma unroll
    for (int ct = 0; ct < 9; ct++) acc[ct] = (f32x4){0.f, 0.f, 0.f, 0.f};
    float s2 = 0.f;

    // raw A holders (named regs; converted after the counted wait)
    f32x4 r0C = {}, r1C = {}, r0N = {}, r1N = {};
    sh8 aCr = {}, aNr = {};

    // prologue: stage k-step 0 (9 DMAs) + raw A(0)
#pragma unroll
    for (int ct = 0; ct < 9; ct++)
        GLL16(gB + ct * FRAGU + l * 8, sB + ct * FRAGU);
    if constexpr (DT) {
        r0C = *(const f32x4*)((const float*)X + aoff);
        r1C = *(const f32x4*)((const float*)X + aoff + 4);
    } else {
        aCr = *(const sh8*)((const u16*)X + aoff);
    }

#pragma unroll
    for (int k = 0; k < KR / 32; k++) {
        if (k < KR / 32 - 1) {
            // issue k+1's 9 fragment-DMAs + raw A — fire and forget
            const u16* g1 = gB + (size_t)(k + 1) * (9 * FRAGU);
            u16* s1 = sB + ((k + 1) & 1) * BUFU;
#pragma unroll
            for (int ct = 0; ct < 9; ct++)
                GLL16(g1 + ct * FRAGU + l * 8, s1 + ct * FRAGU);
            if constexpr (DT) {
                r0N = *(const f32x4*)((const float*)X + aoff + (k + 1) * 32);
                r1N = *(const f32x4*)((const float*)X + aoff + (k + 1) * 32 + 4);
            } else {
                aNr = *(const sh8*)((const u16*)X + aoff + (k + 1) * 32);
            }
            // counted wait: drain k-step k's ops (issued last iter), keep
            // k+1's 11 (DT1: 9 DMA + 2 A) / 10 (DT0: 9 + 1) in flight
            if constexpr (DT) asm volatile("s_waitcnt vmcnt(11)" ::: "memory");
            else              asm volatile("s_waitcnt vmcnt(10)" ::: "memory");
        } else {
            asm volatile("s_waitcnt vmcnt(0)" ::: "memory");
        }

        sh8 a;
        if constexpr (DT) {
#pragma unroll
            for (int i = 0; i < 4; i++) {
                a[i]     = (short)f2bf(r0C[i]);
                a[4 + i] = (short)f2bf(r1C[i]);
            }
        } else {
            a = aCr;
        }
#pragma unroll
        for (int i = 0; i < 8; i++) {
            float xv = bf2f((u16)a[i]);
            s2 = fmaf(xv, xv, s2);
        }
        const u16* bb = sB + (k & 1) * BUFU;
#pragma unroll
        for (int ct = 0; ct < 9; ct++) {
            sh8 b = *(const sh8*)(bb + ct * FRAGU + l * 8);   // ds_read_b128
            acc[ct] = __builtin_amdgcn_mfma_f32_16x16x32_bf16(a, b, acc[ct], 0, 0, 0);
        }
        if constexpr (DT) { r0C = r0N; r1C = r1N; }
        else              { aCr = aNr; }
    }

    // per-token partial sum(x^2) over this K slice: reduce over q
    s2 += __shfl_xor(s2, 16, 64);
    s2 += __shfl_xor(s2, 32, 64);
    if (l < 16) LS2[w][l] = s2;

    // partial P tile -> LP overlay of this wave's OWN staging slab
    // (in-order DS per wave: all staged reads above precede these writes)
    float* LPw = (float*)(BS + w * SLABU);
#pragma unroll
    for (int ct = 0; ct < 9; ct++)
#pragma unroll
        for (int r = 0; r < 4; r++)
            LPw[(q * 4 + r) * LPAD + ct * 16 + m] = acc[ct][r];

    // consts: sum the 8 per-chunk partials per concept into LDS (t<136).
    // Moved post-gemm so its global loads don't perturb the vmcnt counting.
    if (t < 136) {
        int n = t / 17, kk = t % 17;
        float s = 0.f;
#pragma unroll
        for (int j = 0; j < 8; j++) s += gPart[(n * 8 + j) * 17 + kk];
        if (kk == 0)      cMU2[n] = s;
        else if (kk < 9)  cOFF[n][kk - 1] = s;
        else              cUB[n][kk - 9] = s;
    }
    __syncthreads();

    // ---- phase 2: gate (128 threads = 16 tokens x 8 concepts) ----
    if (t < 128) {
        const int tok = t >> 3, n = t & 7;
        float sx2 = 0.f;
#pragma unroll
        for (int u = 0; u < NW; u++) sx2 += LS2[u][tok];

        float pa[8];
#pragma unroll
        for (int s = 0; s < 8; s++) {
            float v = 0.f;
#pragma unroll
            for (int u = 0; u < NW; u++)
                v += ((const float*)(BS + u * SLABU))[tok * LPAD + n * 8 + s];
            pa[s] = v;
        }
        float mdot = 0.f;
#pragma unroll
        for (int u = 0; u < NW; u++)
            mdot += ((const float*)(BS + u * SLABU))[tok * LPAD + 128 + n];

        float norm2 = sx2 - 2.f * mdot + cMU2[n];
        float sc = 0.f;
#pragma unroll
        for (int s = 0; s < 8; s++) {
            float dd = pa[s] - cOFF[n][s];
            sc += dd * dd;
        }
        sc /= norm2;
        float zv = IO<DT>::ld1(SLOPE, n) * (sc - IO<DT>::ld1(CENTER, n));
        int iv = n;
#pragma unroll
        for (int i = 1; i < 8; i <<= 1) {          // first-max tie-break == np.argmax
            float z2 = __shfl_xor(zv, i, 64);
            int   i2 = __shfl_xor(iv, i, 64);
            if (z2 > zv || (z2 == zv && i2 < iv)) { zv = z2; iv = i2; }
        }
        const int c = iv;
        float mxv = 0.f;
#pragma unroll
        for (int u = 0; u < NW; u++)
            mxv += ((const float*)(BS + u * SLABU))[tok * LPAD + 64 + c * 8 + n];
        mxL[tok][n] = mxv - cUB[c][n];
        if (n == 0) { svalL[tok] = 1.f / (1.f + expf(-zv)); cL[tok] = c; }
    }
    __syncthreads();

    // ---- phase 3: blend (512 threads x 4 d's, 16-token loop) ----
    const int d0 = t * 4;
    for (int tok = 0; tok < TPB; ++tok) {
        const int c = cL[tok];
        const float sval = svalL[tok];
        float mxa[8];
#pragma unroll
        for (int h = 0; h < 8; h++) mxa[h] = mxL[tok][h];   // LDS broadcast

        const size_t trow = (size_t)(tok0 + tok) * D;
        float xf[4], bv[4], ov[4];
        IO<DT>::ld4(X,    trow + d0, xf);
        IO<DT>::ld4(BIAS, (size_t)c * D + d0, bv);
#pragma unroll
        for (int i = 0; i < 4; i++) {
            bf16x8 v = *(const bf16x8*)(DGNB + ((size_t)c * D + d0 + i) * 8);
            float du = bf2f(v[0]) * mxa[0] + bf2f(v[1]) * mxa[1]
                     + bf2f(v[2]) * mxa[2] + bf2f(v[3]) * mxa[3]
                     + bf2f(v[4]) * mxa[4] + bf2f(v[5]) * mxa[5]
                     + bf2f(v[6]) * mxa[6] + bf2f(v[7]) * mxa[7];
            ov[i] = (1.f - sval) * xf[i] + sval * (bv[i] + du);   // ETA = 1.0
        }
        IO<DT>::st4(OUT, trow + d0, ov);
    }
}

__global__ __launch_bounds__(512, 2) void k_fused(
    const void* X, const u16* WtT, const float* gPart, const u16* DGNB,
    const void* BIAS, const void* CENTER, const void* SLOPE, void* OUT) {
    // 144 KB: 8 waves x (2 x 9 KB B-staging dbuf); LP tiles overlay per-wave
    __shared__ __align__(16) u16 BS[NW * SLABU];
    __shared__ float LS2[NW][TPB];
    __shared__ float cOFF[8][8], cUB[8][8], cMU2[8];
    __shared__ float mxL[TPB][8], svalL[TPB];
    __shared__ int   cL[TPB];
    if (detect_fp32(X))
        fused_body<1>(X, WtT, gPart, DGNB, BIAS, CENTER, SLOPE, OUT,
                      BS, LS2, cOFF, cUB, cMU2, mxL, svalL, cL);
    else
        fused_body<0>(X, WtT, gPart, DGNB, BIAS, CENTER, SLOPE, OUT,
                      BS, LS2, cOFF, cUB, cMU2, mxL, svalL, cL);
}

// ---------------------------------------------------------------------------
extern "C" void kernel_launch(void* const* d_in, const int* in_sizes, int n_in,
                              void* d_out, int out_size, void* d_ws, size_t ws_size,
                              hipStream_t stream) {
    const void* x      = d_in[0];
    const void* selW   = d_in[1];
    const void* mu     = d_in[2];
    const void* center = d_in[3];
    const void* slope  = d_in[4];
    const void* upd    = d_in[5];
    const void* dgn    = d_in[6];
    const void* biasW  = d_in[7];
    const void* debW   = d_in[8];

    // ws: WtT 576 KB + dgnb 256 KB + gPart 4.3 KB  (~840 KB total).
    char* ws = (char*)d_ws;
    u16*   WtT   = (u16*)ws;                      // 589824 B
    u16*   dgnb  = (u16*)(ws + 589824);           // 262144 B
    float* gPart = (float*)(ws + 851968);         //   4352 B

    k_prep <<<272, 256, 0, stream>>>(x, selW, upd, mu, debW, dgn, WtT, gPart, dgnb);
    k_fused<<<BT / TPB, 512, 0, stream>>>(x, WtT, gPart, dgnb, biasW, center, slope, d_out);
}